// Round 14
// baseline (207.843 us; speedup 1.0000x reference)
//
#include <hip/hip_runtime.h>
#include <hip/hip_bf16.h>

#define BB 20
#define SS 500
#define DIMD 300
#define HIDH 600
#define QKD 128

typedef unsigned short u16;
typedef __attribute__((ext_vector_type(8))) __bf16 bf16x8;
typedef __attribute__((ext_vector_type(8))) short short8;
typedef __attribute__((ext_vector_type(4))) float floatx4;

__device__ __forceinline__ u16 f2bu(float f) {
    __hip_bfloat16 h = __float2bfloat16(f);
    return *reinterpret_cast<u16*>(&h);
}
__device__ __forceinline__ float bu2f(u16 u) {
    unsigned v = ((unsigned)u) << 16;
    return __uint_as_float(v);
}
// fast silu: __expf -> v_exp_f32 (~3 instrs vs ~50 for libm expf).
// error ~1e-6 rel; invisible at bf16 (2^-9) and cannot flip the integer
// gate thresholds (trim=1 is a ~3-4 sigma point; P(|g| within 1e-6 of 1)~0).
__device__ __forceinline__ float silu(float v) {
    return v / (1.f + __expf(-v));
}

__device__ __forceinline__ floatx4 mfma_bf16(short8 a, short8 b, floatx4 c) {
    return __builtin_amdgcn_mfma_f32_16x16x32_bf16(
        __builtin_bit_cast(bf16x8, a), __builtin_bit_cast(bf16x8, b), c, 0, 0, 0);
}

// async global->LDS, 16B/lane; LDS dest = wave-uniform base + lane*16
__device__ __forceinline__ void glds16(const u16* g, u16* l) {
    __builtin_amdgcn_global_load_lds(
        (__attribute__((address_space(1))) const void*)g,
        (__attribute__((address_space(3))) void*)l, 16, 0, 0);
}

__device__ __forceinline__ unsigned fenc(float m) {
    unsigned bits = __float_as_uint(m);
    return (bits & 0x80000000u) ? ~bits : (bits | 0x80000000u);
}

// ---------------- merged prep + LayerNorm/shift ----------------
__global__ __launch_bounds__(256)
void prep_ln_kernel(const float* __restrict__ x, const float* __restrict__ lng,
                    const float* __restrict__ lnb, u16* __restrict__ nxb,
                    const float* __restrict__ Wh, const float* __restrict__ Wqk,
                    const float* __restrict__ Wout, const float* __restrict__ rel_emb,
                    u16* __restrict__ WhT, u16* __restrict__ Wqkb,
                    u16* __restrict__ WoutT, float* __restrict__ bias,
                    int* __restrict__ hist, unsigned* __restrict__ gmaxu,
                    int* __restrict__ h2cm) {
    long id = (long)blockIdx.x * 256 + threadIdx.x;
    if (id < 640000) {                        // LayerNorm + shift, one wave per row
        int bs = id >> 6;
        int t = id & 63;
        int s = bs % SS;
        const float* xr = x + (long)bs * DIMD;
        float sum = 0.f, sq = 0.f;
        for (int d = t; d < DIMD; d += 64) { float v = xr[d]; sum += v; sq += v * v; }
        for (int off = 1; off < 64; off <<= 1) {
            sum += __shfl_xor(sum, off);
            sq  += __shfl_xor(sq, off);
        }
        float mean = sum * (1.f / DIMD);
        float var  = sq * (1.f / DIMD) - mean * mean;
        float rstd = rsqrtf(var + 1e-5f);
        for (int d = t; d < DIMD; d += 64) {
            float nv = (xr[d] - mean) * rstd * lng[d] + lnb[d];
            if (d < DIMD / 2) {
                if (s < SS - 1) nxb[(long)(bs + 1) * 320 + d] = f2bu(nv);
            } else {
                nxb[(long)bs * 320 + d] = f2bu(nv);
            }
        }
        if (s == 0)
            for (int d = t; d < DIMD / 2; d += 64) nxb[(long)bs * 320 + d] = 0;
        for (int d = DIMD + t; d < 320; d += 64) nxb[(long)bs * 320 + d] = 0;
        return;
    }
    id -= 640000;
    if (id < 384000) {                        // WhT[n][k], k<320
        int k = id / 1200, n = id - (long)k * 1200;
        WhT[(long)n * 320 + k] = (k < 300) ? f2bu(Wh[(long)k * 1200 + n]) : (u16)0;
        return;
    }
    id -= 384000;
    if (id < 40960) {                         // Wqkb[n][k]
        int k = id / 128, n = id - (long)k * 128;
        Wqkb[(long)n * 320 + k] = (k < 300) ? f2bu(Wqk[(long)k * 128 + n]) : (u16)0;
        return;
    }
    id -= 40960;
    if (id < 182400) {                        // WoutT[n][k], k<608
        int k = id / 300, n = id - (long)k * 300;
        WoutT[(long)n * 608 + k] = (k < 600) ? f2bu(Wout[(long)k * 300 + n]) : (u16)0;
        return;
    }
    id -= 182400;
    if (id < 250000) {                        // T5 bias 500x500
        int i = id / 500, j = id - (long)i * 500;
        int n = i - j;
        int ret = (n < 0) ? 16 : 0;
        int na = n < 0 ? -n : n;
        int bucket;
        if (na < 8) bucket = ret + na;
        else {
            int vil = 8 + (int)(logf((float)na * 0.125f) / logf(16.f) * 8.f);
            vil = vil < 15 ? vil : 15;
            bucket = ret + vil;
        }
        bias[id] = rel_emb[bucket] * 11.313708498984761f;
        return;
    }
    id -= 250000;
    if (id < 5120) { hist[id] = 0; return; }   // 20 batches x 256-int stride
    id -= 5120;
    if (id < 1280) { gmaxu[id] = 0u; return; } // 20 batches x 64-uint stride
    id -= 1280;
    if (id < 1280) h2cm[(int)id] = 0;          // h2 hist (20x32) + cmax (20x32)
}

// ---------------- Epilogues ----------------
// All epilogues implement: init(bz) pre-K-loop hook, operator()(acc,bz,m,n,j)
// with j = compile-time n-subtile slot (0/1), finish(bz,m0,n0) post hook.

// EpiH: gemm1 transposed (m = hidden [0,1200), n = token [0,10000)).
// Fuses gate stats (saves re-reading 24MB of gateT):
//   - hist: |g|>=1 is a ~3-4 sigma tail -> ~25k atomics total.
//   - gmax: per-lane running max per STATIC n-slot (R2 lesson: per-call
//     column tracking serialized the unrolled epilogue; slot j is compile
//     time).  Column groups are 16-aligned, 10000%16==0 -> group validity
//     and (usually) batch are wave-uniform; straddling groups (500%16!=0)
//     fall back to per-column atomics from lanes 0..15.
struct EpiH {
    const float* bh; u16* vT; float* gateT; int* hist; unsigned* gmaxu;
    float gm0 = -1e30f, gm1 = -1e30f;
    __device__ void init(int) {}
    __device__ void operator()(float acc, int bz, int m, int n, int j) {
        if (m >= 1200 || n >= 10000) return;
        float v = silu(acc + bh[m]);
        int b = n / SS, s = n - b * SS;
        if (m < HIDH) { vT[((long)b * 640 + m) * 512 + s] = f2bu(v); return; }
        gateT[((long)b * HIDH + (m - HIDH)) * SS + s] = v;
        if (j) gm1 = fmaxf(gm1, v); else gm0 = fmaxf(gm0, v);
        float ag = fabsf(v);
        if (ag >= 1.f) {
            int bin = (int)fminf(floorf(ag), 128.f);
            atomicAdd(&hist[b * 256 + bin], 1);
        }
    }
    __device__ void flushS(float m, int base) {
        if (base >= 10000) return;
        m = fmaxf(m, __shfl_xor(m, 16));       // reduce over l4 (same column)
        m = fmaxf(m, __shfl_xor(m, 32));
        int b0 = base / SS;
        if (b0 == (base + 15) / SS) {          // batch-uniform column group
            m = fmaxf(m, __shfl_xor(m, 1));
            m = fmaxf(m, __shfl_xor(m, 2));
            m = fmaxf(m, __shfl_xor(m, 4));
            m = fmaxf(m, __shfl_xor(m, 8));
            if ((threadIdx.x & 63) == 0 && m > -1e29f)
                atomicMax(&gmaxu[b0 * 64], fenc(m));
        } else {                               // group straddles batch edge
            int l = threadIdx.x & 63;
            if (l < 16 && m > -1e29f)
                atomicMax(&gmaxu[((base + l) / SS) * 64], fenc(m));
        }
    }
    __device__ void finish(int bz, int m0, int n0) {
        if (m0 + 32 <= 600) return;            // wave has no gate rows
        flushS(gm0, n0);
        flushS(gm1, n0 + 16);
    }
};
struct EpiQKRot {        // qk + silu + gamma/beta + rotary (NO early return: shuffles)
    const float* bqk; const float* gamma; const float* beta;
    u16* qb; u16* kb;
    __device__ void init(int) const {}
    __device__ void operator()(float acc, int bz, int m, int n, int j) const {
        float v = silu(acc + bqk[n]);
        float qp = v * gamma[n] + beta[n];
        float kp = v * gamma[QKD + n] + beta[QKD + n];
        float qx = __shfl_xor(qp, 1);
        float kx = __shfl_xor(kp, 1);
        float qo = qp, ko = kp;
        if (n < 32) {
            int s = m % SS;
            float inv = expf(-(float)(n & ~1) * (logf(10000.f) / 32.f));
            float ang = (float)s * inv;
            float c, sn;
            sincosf(ang, &sn, &c);
            float qr = (n & 1) ? qx : -qx;
            float kr = (n & 1) ? kx : -kx;
            qo = qp * c + qr * sn;
            ko = kp * c + kr * sn;
        }
        if (m < 10000) {
            qb[(long)m * QKD + n] = f2bu(qo);
            kb[(long)m * QKD + n] = f2bu(ko);
        }
    }
    __device__ void finish(int, int, int) const {}
};
struct EpiAttnB {        // scores -> (relu((s+bias)/S))^2 * mask -> bf16 [500][512]
    const float* bias; const float* mask; u16* attnb;
    __device__ void init(int) const {}
    __device__ void operator()(float acc, int b, int m, int n, int j) const {
        if (m >= SS || n >= 512) return;
        float r = 0.f;
        if (n < SS) {
            float s = (acc + bias[m * SS + n]) * (1.f / (float)SS);
            s = fmaxf(s, 0.f);
            r = s * s * mask[m * SS + n];
        }
        attnb[((long)b * SS + m) * 512 + n] = f2bu(r);
    }
    __device__ void finish(int, int, int) const {}
};
struct EpiGateN {        // gated = gm * (attn@v) * gate -> bf16 [10000][608]
    // reads gateT fp32 directly (batch slice is 1.2MB, mostly L2/L3).
    // t2[b] computed per-thread in init() (17 uniform L2 loads, hidden
    // under the staging prologue).
    const float* gateT; const int* counts; const int* h2cm; u16* gated;
    int t2 = 0;
    __device__ void init(int b) {
        int cmax = h2cm[640 + b * 32];
        int suffix = 0, best = 0;
        bool found = false;
        for (int tt = 16; tt >= 1; --tt) {
            suffix += h2cm[b * 32 + tt];
            if (!found && tt <= cmax && suffix > 3600) { best = tt; found = true; }
        }
        t2 = found ? best : cmax;
    }
    __device__ void operator()(float acc, int b, int m, int n, int j) const {
        if (m >= SS || n >= 608) return;
        float r = 0.f;
        if (n < HIDH) {
            float g = gateT[((long)b * HIDH + n) * SS + m];
            int c = counts[(b * 100 + m / 5) * 120 + n / 5];
            float bv = (c >= t2) ? 1.f : 0.25f;
            float p = ((m % 5) == 4 || (n % 5) == 4) ? 0.f : 1.f;
            r = acc * g * bv * p;
        }
        gated[((long)(b * SS + m)) * 608 + n] = f2bu(r);
    }
    __device__ void finish(int, int, int) const {}
};
struct EpiOutB {         // out = gated@Wout + bout + x
    const float* bout; const float* x; float* out;
    __device__ void init(int) const {}
    __device__ void operator()(float acc, int b, int m, int n, int j) const {
        if (m >= 10000 || n >= DIMD) return;
        out[(long)m * DIMD + n] = acc + bout[n] + x[(long)m * DIMD + n];
    }
    __device__ void finish(int, int, int) const {}
};

// ---------------- cooperative-staged bf16 MFMA GEMM body ----------------
// R14: NBUF per dispatch, assigned by OCCUPANCY ARITHMETIC (not K alone):
//   NBUF=2 (16KB, 8 blocks/CU) ONLY where grid/CU > 6 (residency-capped):
//     sc (2220 blocks = 8.7/CU).  R12 measured the -6us gain here.
//   NBUF=3 (24KB, counted vmcnt(2), prefetch dist 2) everywhere else:
//     qk_h (3360 blocks but steady-state-dominated K=320; R11 41.3us vs
//     44.8 at NBUF=2), attn@v (1600 blocks = 6.25/CU ~= the 6/CU NBUF=3
//     cap -> residency identical, prefetch free), out (800 blocks =
//     3.1/CU -> GRID-limited, NBUF choice costs zero residency; K=608 is
//     the longest K in the net -> counted prefetch strictly wins).
// Common, proven elements: cooperative staging (waves 0,1->A rows, 2,3->B
// rows; 2 glds/wave/step), XOR swizzle (conflicts 2.1M->0, zero per-step
// cost), RAW s_barrier + compiler fence (rule-18), __expf silu.
// R9 lesson: glds staging is load-bearing (direct-to-reg = compiler won't
// pipeline scattered frag loads, 2x slower).
// Sync per step: s_waitcnt vmcnt(N) lgkmcnt(0) [N=2 while >=1 step remains
// at NBUF=3, else 0] -> s_barrier -> fence -> prefetch into the buffer
// whose readers all drained before this barrier -> 4 ds_read + 4 MFMA.
// Swizzle (rule-21, both-sides with glds): LDS linear; GLOBAL source chunk
// c' = c ^ ((srow>>1)&3); read chunk l4 ^ ((l15>>1)&3) (compile-time per
// lane: frag row bases are multiples of 16).
// 1-D grid, XCD pinning (workgroup->XCD is round-robin on linear id):
//   MODE 0: batch g -> XCD g%8 (unbalanced for bound=20; reference only).
//   MODE 1: slice N per-XCD (TX groups).  MODE 2: slice M per-XCD.
//   MODE 3: BALANCED batch map for 20 batches (TY==8): XCD x gets batches
//           2x,2x+1 full + half of batch 16+(x&3) (row-band split keeps
//           scores->attn@v attnb tiles on the producing XCD).
// Early whole-block return is uniform and pre-barrier.  Staging has NO
// bounds checks: overruns read adjacent ws buffers (audited in-bounds for
// every call site); garbage only reaches acc rows/cols whose epilogue
// writes are guarded off; K-pads are real zeros.
template<int MODE, int NBUF, class Epi>
__device__ __forceinline__ void gemm_body(
        int lin, u16* __restrict__ S,
        const u16* __restrict__ A, const u16* __restrict__ Bt,
        int Kp, int lda, int ldb, long sA, long sB,
        int TX, int TY, int bound, Epi epi) {
    int xcd = lin & 7, i = lin >> 3;
    int bx, by, bz;
    if (MODE == 3) {                    // balanced 20-batch map (TY==8)
        int P = TX << 3;                // tiles per batch
        int half = P >> 1;
        int tl;
        if (i < 2 * P) {
            bz = (xcd << 1) + (i >= P ? 1 : 0);
            tl = (i >= P) ? i - P : i;
        } else {
            bz = 16 + (xcd & 3);
            tl = (i - 2 * P) + ((xcd & 4) ? half : 0);
        }
        bx = tl % TX; by = tl / TX;
    } else {
        int per = TX * TY;
        int w = i / per;
        int tl = i - w * per;
        int g = xcd + (w << 3);
        int tx = tl % TX, ty = tl / TX;
        if (MODE == 0)      { if (g >= bound) return; bx = tx; by = ty; bz = g; }
        else if (MODE == 1) { bx = g * TX + tx; if (bx >= bound) return; by = ty; bz = 0; }
        else                { by = g * TY + ty; if (by >= bound) return; bx = tx; bz = 0; }
    }

    A += (long)bz * sA; Bt += (long)bz * sB;
    int t = threadIdx.x, lane = t & 63, wave = t >> 6;
    int l15 = lane & 15, l4 = lane >> 4;
    int mw = (wave >> 1) << 5, nw = (wave & 1) << 5;
    int m0 = (by << 6) + mw;
    int n0 = (bx << 6) + nw;

    // staging: lane covers (row r=lane>>2, chunk c=lane&3) of a 16-row block;
    // source chunk XOR-swizzled: c' = c ^ ((r>>1)&3)
    int srow = lane >> 2;
    int scol = ((lane & 3) ^ ((srow >> 1) & 3)) << 3;
    const u16* gp0;
    int drow;
    if (wave < 2) {
        gp0 = A + (long)((by << 6) + (wave << 5) + srow) * lda + scol;
        drow = wave << 5;
    } else {
        gp0 = Bt + (long)((bx << 6) + ((wave - 2) << 5) + srow) * ldb + scol;
        drow = 64 + ((wave - 2) << 5);
    }
    const u16* gp1 = gp0 + (long)16 * (wave < 2 ? lda : ldb);
    u16* d0 = S + drow * 32;
    u16* d1 = S + (drow + 16) * 32;

    floatx4 acc[2][2];
#pragma unroll
    for (int i2 = 0; i2 < 2; ++i2)
#pragma unroll
        for (int j = 0; j < 2; ++j) acc[i2][j] = (floatx4){0.f, 0.f, 0.f, 0.f};

    int nsteps = Kp >> 5;
    // prologue: stage buffers 0..NBUF-2
    glds16(gp0, d0);
    glds16(gp1, d1);
    if constexpr (NBUF == 3) {
        if (nsteps > 1) { glds16(gp0 + 32, d0 + 4096); glds16(gp1 + 32, d1 + 4096); }
    }

    epi.init(bz);                              // hidden under staging latency

    // read chunk: frag row bases are multiples of 16 -> ((row>>1)&3) == ((l15>>1)&3)
    int rchunk = (l4 ^ ((l15 >> 1) & 3)) << 3;

    int bufc = 0;                              // current buffer index (si % NBUF)
    for (int si = 0; si < nsteps; ++si) {
        if constexpr (NBUF == 3) {
            if (si + 1 < nsteps)
                asm volatile("s_waitcnt vmcnt(2) lgkmcnt(0)" ::: "memory");
            else
                asm volatile("s_waitcnt vmcnt(0) lgkmcnt(0)" ::: "memory");
        } else {
            asm volatile("s_waitcnt vmcnt(0) lgkmcnt(0)" ::: "memory");
        }
        __builtin_amdgcn_s_barrier();
        asm volatile("" ::: "memory");         // pin ds_reads below barrier
        int kn = (si + NBUF - 1) << 5;
        if (kn < Kp) {                         // prefetch distance NBUF-1
            int bufp = (bufc == 0) ? NBUF - 1 : bufc - 1;   // (si+NBUF-1)%NBUF
            glds16(gp0 + kn, d0 + bufp * 4096);
            glds16(gp1 + kn, d1 + bufp * 4096);
        }
        const u16* SB = S + bufc * 4096;
        short8 a0 = *(const short8*)(SB + ((mw + l15) << 5) + rchunk);
        short8 a1 = *(const short8*)(SB + ((mw + 16 + l15) << 5) + rchunk);
        short8 b0 = *(const short8*)(SB + ((64 + nw + l15) << 5) + rchunk);
        short8 b1 = *(const short8*)(SB + ((64 + nw + 16 + l15) << 5) + rchunk);
        acc[0][0] = mfma_bf16(a0, b0, acc[0][0]);
        acc[0][1] = mfma_bf16(a0, b1, acc[0][1]);
        acc[1][0] = mfma_bf16(a1, b0, acc[1][0]);
        acc[1][1] = mfma_bf16(a1, b1, acc[1][1]);
        bufc = (bufc + 1 == NBUF) ? 0 : bufc + 1;
    }
#pragma unroll
    for (int i2 = 0; i2 < 2; ++i2) {
        int bm = m0 + (i2 << 4) + (l4 << 2);
#pragma unroll
        for (int j = 0; j < 2; ++j) {
            int bn = n0 + (j << 4) + l15;
#pragma unroll
            for (int r = 0; r < 4; ++r)
                epi(acc[i2][j][r], bz, bm + r, bn, j);
        }
    }
    epi.finish(bz, m0, n0);
}

// standalone wrapper (static LDS = NBUF*8KB)
template<int MODE, int NBUF, class Epi>
__global__ __launch_bounds__(256)
void gemm_nb(const u16* __restrict__ A, const u16* __restrict__ Bt,
             int Kp, int lda, int ldb, long sA, long sB,
             int TX, int TY, int bound, Epi epi) {
    __shared__ __align__(16) u16 S[NBUF * 4096];
    gemm_body<MODE, NBUF>(blockIdx.x, S, A, Bt, Kp, lda, ldb, sA, sB, TX, TY, bound, epi);
}

// merged qk-gemm (blocks [0,320)) + h-gemm (blocks [320,3360)).  Independent,
// both read nxb, both latency-bound -> overlap in one launch.  Offset
// 320%8==0 preserves the h-gemm's XCD slicing.  NBUF=3 (long-K config,
// R11-measured best).  Dynamic LDS 24KB.
__global__ __launch_bounds__(256)
void gemm_qk_h(const u16* __restrict__ nxb, const u16* __restrict__ Wqkb,
               const u16* __restrict__ WhT, EpiQKRot eq, EpiH eh) {
    extern __shared__ u16 S[];
    int lin = blockIdx.x;
    if (lin < 320)
        gemm_body<2, 3>(lin, S, nxb, Wqkb, 320, 320, 320, 0L, 0L, 2, 20, 157, eq);
    else
        gemm_body<1, 3>(lin - 320, S, WhT, nxb, 320, 320, 320, 0L, 0L, 20, 19, 157, eh);
}

// merged scores-gemm (blocks [0,1280), MODE 3 balanced, NBUF=2 residency
// config) + counts ([1280,2220)).  counts: 47 blocks per batch; per-block
// LDS h2-hist + max, one atomicAdd per bin per block into h2cm.
__global__ __launch_bounds__(256)
void gemm_sc(const u16* __restrict__ qb, const u16* __restrict__ kb, EpiAttnB ea,
             const float* __restrict__ gateT, const int* __restrict__ hist,
             const unsigned* __restrict__ gmaxu, int* __restrict__ counts,
             int* __restrict__ h2cm) {
    extern __shared__ u16 S[];
    int lin = blockIdx.x;
    if (lin < 1280) {
        gemm_body<3, 2>(lin, S, qb, kb, QKD, QKD, QKD,
                        (long)SS * QKD, (long)SS * QKD, 8, 8, BB, ea);
        return;
    }
    int cb = lin - 1280;
    int b = cb / 47, blk = cb - b * 47;
    int r = blk * 256 + threadIdx.x;
    int* h2l = (int*)S;
    int* smaxp = h2l + 17;
    if (threadIdx.x < 17) h2l[threadIdx.x] = 0;
    if (threadIdx.x == 0) *smaxp = 0;
    __syncthreads();
    int c = 0;
    if (r < 12000) {
        unsigned enc = gmaxu[b * 64];
        unsigned bits = (enc & 0x80000000u) ? (enc & 0x7FFFFFFFu) : ~enc;
        float gmax = floorf(__uint_as_float(bits));
        int suffix = 0, trim = 1;
        for (int tt = 128; tt >= 1; --tt) {
            suffix += hist[b * 256 + tt];
            if ((float)tt <= gmax && suffix > 90000) { trim = tt; break; }
        }
        float tr = (float)trim;
        int bi = r / 120, bj = r - bi * 120;
        const float* gb = gateT + (long)b * SS * HIDH;
#pragma unroll
        for (int cc = 0; cc < 4; ++cc)
#pragma unroll
            for (int rr = 0; rr < 4; ++rr) {
                float gv = gb[(long)(bj * 5 + cc) * SS + bi * 5 + rr];
                c += (fabsf(gv) >= tr) ? 1 : 0;
            }
        counts[b * 12000 + r] = c;
        if (c) atomicAdd(&h2l[c], 1);
    }
    int lmax = c;
    for (int off = 32; off; off >>= 1) {
        int o = __shfl_xor(lmax, off);
        lmax = lmax > o ? lmax : o;
    }
    if ((threadIdx.x & 63) == 0) atomicMax(smaxp, lmax);
    __syncthreads();
    if (threadIdx.x < 17 && h2l[threadIdx.x])
        atomicAdd(&h2cm[b * 32 + threadIdx.x], h2l[threadIdx.x]);
    if (threadIdx.x == 0) atomicMax(&h2cm[640 + b * 32], *smaxp);
}

extern "C" void kernel_launch(void* const* d_in, const int* in_sizes, int n_in,
                              void* d_out, int out_size, void* d_ws, size_t ws_size,
                              hipStream_t stream) {
    const float* x      = (const float*)d_in[0];
    const float* mask2  = (const float*)d_in[1];
    const float* ln_g   = (const float*)d_in[2];
    const float* ln_b   = (const float*)d_in[3];
    const float* Wh     = (const float*)d_in[4];
    const float* bh     = (const float*)d_in[5];
    const float* Wqk    = (const float*)d_in[6];
    const float* bqk    = (const float*)d_in[7];
    const float* gamma  = (const float*)d_in[8];
    const float* beta   = (const float*)d_in[9];
    const float* rel_emb= (const float*)d_in[10];
    const float* Wout   = (const float*)d_in[11];
    const float* bout   = (const float*)d_in[12];
    float* out = (float*)d_out;
    float* ws  = (float*)d_ws;

    // workspace layout (float offsets; all 16B-aligned)
    float* gateT  = ws;                            //  6,000,000 f
    float* bias   = ws + 6000000;                  //    250,000 f
    u16*   nxb    = (u16*)(ws + 6250000);          // 10000x320 u16
    u16*   WhT    = (u16*)(ws + 7850000);          //  1200x320 u16
    u16*   Wqkb   = (u16*)(ws + 8042000);          //   128x320 u16
    u16*   WoutT  = (u16*)(ws + 8062480);          //   300x608 u16
    u16*   qb     = (u16*)(ws + 8153680);          // 10000x128 u16
    u16*   kb     = (u16*)(ws + 8793680);          // 10000x128 u16
    u16*   attnb  = (u16*)(ws + 9433680);          // 20x500x512 u16
    u16*   vT     = (u16*)(ws + 11993680);         // 20x640x512 u16
    u16*   gatedb = (u16*)(ws + 15270480);         // 10000x608 u16
    int*   hist   = (int*)(ws + 21310480);         // 20 x 256-int stride
    unsigned* gmaxu = (unsigned*)(ws + 21315600);  // 20 x 64-uint stride
    int*   counts = (int*)(ws + 21316880);         //   240,000
    int*   h2cm   = (int*)(ws + 21556880);         // h2 20x32 + cmax 20x32

    // 1. prep + LN; also zeroes hist/gmaxu/h2cm
    prep_ln_kernel<<<5880, 256, 0, stream>>>(x, ln_g, ln_b, nxb, Wh, Wqk, Wout,
                                             rel_emb, WhT, Wqkb, WoutT, bias,
                                             hist, gmaxu, h2cm);

    // 2. MERGED: qk gemm + silu/rotary (M=10000,N=128,Kp=320; 320 blocks)
    //    || h gemm -> vT bf16 + gateT fp32 + fused hist/gmax
    //    (M=1200,N=10000,Kp=320; 3040 blocks).  NBUF=3 / 24KB.
    gemm_qk_h<<<3360, 256, 24576, stream>>>(
        nxb, Wqkb, WhT,
        EpiQKRot{bqk, gamma, beta, qb, kb},
        EpiH{bh, vT, gateT, hist, gmaxu});

    // 3. MERGED: scores -> attnb bf16 (MODE 3 balanced: each XCD 2.5
    //    batches, row-band split; 1280 blocks; NBUF=2 / 16KB --
    //    residency-capped at 8.7 blocks/CU, R12-measured win)
    //    || counts (940 blocks)
    gemm_sc<<<2220, 256, 16384, stream>>>(
        qb, kb, EpiAttnB{bias, mask2, attnb},
        gateT, hist, gmaxu, counts, h2cm);

    // 4. attn@v + fused gate mask (per batch 500x640, Kp=512): MODE 3
    //    balanced (1600 blocks = 6.25/CU ~= NBUF=3's 6/CU residency cap
    //    -> counted prefetch is free).  NBUF=3 / 24KB.  Row-band split
    //    matches scores so attnb tiles are read from the producing XCD's
    //    L2.  t2[b] derived per-thread in epi.init from h2cm.
    gemm_nb<3, 3><<<1600, 256, 0, stream>>>(
        attnb, vT, 512, 512, 512,
        (long)SS * 512, (long)640 * 512, 10, 8, BB,
        EpiGateN{gateT, counts, h2cm, gatedb});

    // 5. out = gated@Wout + bout + x (M=10000, N=300, Kp=608): slice M
    //    over XCDs, TX=5 n-tiles.  800 blocks = 3.1/CU -> GRID-limited,
    //    NBUF=3 costs zero residency; K=608 longest in net.  NBUF=3/24KB.
    gemm_nb<2, 3><<<8 * 5 * 20, 256, 0, stream>>>(
        gatedb, WoutT, 608, 608, 608, 0L, 0L, 5, 20, 157, EpiOutB{bout, x, out});
}

// Round 15
// 205.490 us; speedup vs baseline: 1.0115x; 1.0115x over previous
//
#include <hip/hip_runtime.h>
#include <hip/hip_bf16.h>

#define BB 20
#define SS 500
#define DIMD 300
#define HIDH 600
#define QKD 128

typedef unsigned short u16;
typedef __attribute__((ext_vector_type(8))) __bf16 bf16x8;
typedef __attribute__((ext_vector_type(8))) short short8;
typedef __attribute__((ext_vector_type(4))) float floatx4;

__device__ __forceinline__ u16 f2bu(float f) {
    __hip_bfloat16 h = __float2bfloat16(f);
    return *reinterpret_cast<u16*>(&h);
}
__device__ __forceinline__ float bu2f(u16 u) {
    unsigned v = ((unsigned)u) << 16;
    return __uint_as_float(v);
}
// fast silu: __expf -> v_exp_f32 (~3 instrs vs ~50 for libm expf).
// error ~1e-6 rel; invisible at bf16 (2^-9) and cannot flip the integer
// gate thresholds (trim=1 is a ~3-4 sigma point; P(|g| within 1e-6 of 1)~0).
__device__ __forceinline__ float silu(float v) {
    return v / (1.f + __expf(-v));
}

__device__ __forceinline__ floatx4 mfma_bf16(short8 a, short8 b, floatx4 c) {
    return __builtin_amdgcn_mfma_f32_16x16x32_bf16(
        __builtin_bit_cast(bf16x8, a), __builtin_bit_cast(bf16x8, b), c, 0, 0, 0);
}

// async global->LDS, 16B/lane; LDS dest = wave-uniform base + lane*16
__device__ __forceinline__ void glds16(const u16* g, u16* l) {
    __builtin_amdgcn_global_load_lds(
        (__attribute__((address_space(1))) const void*)g,
        (__attribute__((address_space(3))) void*)l, 16, 0, 0);
}

__device__ __forceinline__ unsigned fenc(float m) {
    unsigned bits = __float_as_uint(m);
    return (bits & 0x80000000u) ? ~bits : (bits | 0x80000000u);
}

// ---------------- merged prep + LayerNorm/shift ----------------
__global__ __launch_bounds__(256)
void prep_ln_kernel(const float* __restrict__ x, const float* __restrict__ lng,
                    const float* __restrict__ lnb, u16* __restrict__ nxb,
                    const float* __restrict__ Wh, const float* __restrict__ Wqk,
                    const float* __restrict__ Wout, const float* __restrict__ rel_emb,
                    u16* __restrict__ WhT, u16* __restrict__ Wqkb,
                    u16* __restrict__ WoutT, float* __restrict__ bias,
                    int* __restrict__ hist, unsigned* __restrict__ gmaxu,
                    int* __restrict__ h2cm) {
    long id = (long)blockIdx.x * 256 + threadIdx.x;
    if (id < 640000) {                        // LayerNorm + shift, one wave per row
        int bs = id >> 6;
        int t = id & 63;
        int s = bs % SS;
        const float* xr = x + (long)bs * DIMD;
        float sum = 0.f, sq = 0.f;
        for (int d = t; d < DIMD; d += 64) { float v = xr[d]; sum += v; sq += v * v; }
        for (int off = 1; off < 64; off <<= 1) {
            sum += __shfl_xor(sum, off);
            sq  += __shfl_xor(sq, off);
        }
        float mean = sum * (1.f / DIMD);
        float var  = sq * (1.f / DIMD) - mean * mean;
        float rstd = rsqrtf(var + 1e-5f);
        for (int d = t; d < DIMD; d += 64) {
            float nv = (xr[d] - mean) * rstd * lng[d] + lnb[d];
            if (d < DIMD / 2) {
                if (s < SS - 1) nxb[(long)(bs + 1) * 320 + d] = f2bu(nv);
            } else {
                nxb[(long)bs * 320 + d] = f2bu(nv);
            }
        }
        if (s == 0)
            for (int d = t; d < DIMD / 2; d += 64) nxb[(long)bs * 320 + d] = 0;
        for (int d = DIMD + t; d < 320; d += 64) nxb[(long)bs * 320 + d] = 0;
        return;
    }
    id -= 640000;
    if (id < 384000) {                        // WhT[n][k], k<320
        int k = id / 1200, n = id - (long)k * 1200;
        WhT[(long)n * 320 + k] = (k < 300) ? f2bu(Wh[(long)k * 1200 + n]) : (u16)0;
        return;
    }
    id -= 384000;
    if (id < 40960) {                         // Wqkb[n][k]
        int k = id / 128, n = id - (long)k * 128;
        Wqkb[(long)n * 320 + k] = (k < 300) ? f2bu(Wqk[(long)k * 128 + n]) : (u16)0;
        return;
    }
    id -= 40960;
    if (id < 182400) {                        // WoutT[n][k], k<608
        int k = id / 300, n = id - (long)k * 300;
        WoutT[(long)n * 608 + k] = (k < 600) ? f2bu(Wout[(long)k * 300 + n]) : (u16)0;
        return;
    }
    id -= 182400;
    if (id < 250000) {                        // T5 bias 500x500
        int i = id / 500, j = id - (long)i * 500;
        int n = i - j;
        int ret = (n < 0) ? 16 : 0;
        int na = n < 0 ? -n : n;
        int bucket;
        if (na < 8) bucket = ret + na;
        else {
            int vil = 8 + (int)(logf((float)na * 0.125f) / logf(16.f) * 8.f);
            vil = vil < 15 ? vil : 15;
            bucket = ret + vil;
        }
        bias[id] = rel_emb[bucket] * 11.313708498984761f;
        return;
    }
    id -= 250000;
    if (id < 5120) { hist[id] = 0; return; }   // 20 batches x 256-int stride
    id -= 5120;
    if (id < 1280) { gmaxu[id] = 0u; return; } // 20 batches x 64-uint stride
    id -= 1280;
    if (id < 1280) h2cm[(int)id] = 0;          // h2 hist (20x32) + cmax (20x32)
}

// ---------------- Epilogues ----------------
// All epilogues implement: init(bz) pre-K-loop hook, operator()(acc,bz,m,n,j)
// with j = compile-time n-subtile slot (0/1), finish(bz,m0,n0) post hook.

// EpiH: gemm1 transposed (m = hidden [0,1200), n = token [0,10000)).
// Fuses gate stats (saves re-reading 24MB of gateT):
//   - hist: |g|>=1 is a ~3-4 sigma tail -> ~25k atomics total.
//   - gmax: per-lane running max per STATIC n-slot (R2 lesson: per-call
//     column tracking serialized the unrolled epilogue; slot j is compile
//     time).  Column groups are 16-aligned, 10000%16==0 -> group validity
//     and (usually) batch are wave-uniform; straddling groups (500%16!=0)
//     fall back to per-column atomics from lanes 0..15.
struct EpiH {
    const float* bh; u16* vT; float* gateT; int* hist; unsigned* gmaxu;
    float gm0 = -1e30f, gm1 = -1e30f;
    __device__ void init(int) {}
    __device__ void operator()(float acc, int bz, int m, int n, int j) {
        if (m >= 1200 || n >= 10000) return;
        float v = silu(acc + bh[m]);
        int b = n / SS, s = n - b * SS;
        if (m < HIDH) { vT[((long)b * 640 + m) * 512 + s] = f2bu(v); return; }
        gateT[((long)b * HIDH + (m - HIDH)) * SS + s] = v;
        if (j) gm1 = fmaxf(gm1, v); else gm0 = fmaxf(gm0, v);
        float ag = fabsf(v);
        if (ag >= 1.f) {
            int bin = (int)fminf(floorf(ag), 128.f);
            atomicAdd(&hist[b * 256 + bin], 1);
        }
    }
    __device__ void flushS(float m, int base) {
        if (base >= 10000) return;
        m = fmaxf(m, __shfl_xor(m, 16));       // reduce over l4 (same column)
        m = fmaxf(m, __shfl_xor(m, 32));
        int b0 = base / SS;
        if (b0 == (base + 15) / SS) {          // batch-uniform column group
            m = fmaxf(m, __shfl_xor(m, 1));
            m = fmaxf(m, __shfl_xor(m, 2));
            m = fmaxf(m, __shfl_xor(m, 4));
            m = fmaxf(m, __shfl_xor(m, 8));
            if ((threadIdx.x & 63) == 0 && m > -1e29f)
                atomicMax(&gmaxu[b0 * 64], fenc(m));
        } else {                               // group straddles batch edge
            int l = threadIdx.x & 63;
            if (l < 16 && m > -1e29f)
                atomicMax(&gmaxu[((base + l) / SS) * 64], fenc(m));
        }
    }
    __device__ void finish(int bz, int m0, int n0) {
        if (m0 + 32 <= 600) return;            // wave has no gate rows
        flushS(gm0, n0);
        flushS(gm1, n0 + 16);
    }
};
struct EpiQKRot {        // qk + silu + gamma/beta + rotary (NO early return: shuffles)
    const float* bqk; const float* gamma; const float* beta;
    u16* qb; u16* kb;
    __device__ void init(int) const {}
    __device__ void operator()(float acc, int bz, int m, int n, int j) const {
        float v = silu(acc + bqk[n]);
        float qp = v * gamma[n] + beta[n];
        float kp = v * gamma[QKD + n] + beta[QKD + n];
        float qx = __shfl_xor(qp, 1);
        float kx = __shfl_xor(kp, 1);
        float qo = qp, ko = kp;
        if (n < 32) {
            int s = m % SS;
            float inv = expf(-(float)(n & ~1) * (logf(10000.f) / 32.f));
            float ang = (float)s * inv;
            float c, sn;
            sincosf(ang, &sn, &c);
            float qr = (n & 1) ? qx : -qx;
            float kr = (n & 1) ? kx : -kx;
            qo = qp * c + qr * sn;
            ko = kp * c + kr * sn;
        }
        if (m < 10000) {
            qb[(long)m * QKD + n] = f2bu(qo);
            kb[(long)m * QKD + n] = f2bu(ko);
        }
    }
    __device__ void finish(int, int, int) const {}
};
struct EpiAttnB {        // scores -> (relu((s+bias)/S))^2 * mask -> bf16 [500][512]
    const float* bias; const float* mask; u16* attnb;
    __device__ void init(int) const {}
    __device__ void operator()(float acc, int b, int m, int n, int j) const {
        if (m >= SS || n >= 512) return;
        float r = 0.f;
        if (n < SS) {
            float s = (acc + bias[m * SS + n]) * (1.f / (float)SS);
            s = fmaxf(s, 0.f);
            r = s * s * mask[m * SS + n];
        }
        attnb[((long)b * SS + m) * 512 + n] = f2bu(r);
    }
    __device__ void finish(int, int, int) const {}
};
struct EpiGateN {        // gated = gm * (attn@v) * gate -> bf16 [10000][608]
    // reads gateT fp32 directly (batch slice is 1.2MB, mostly L2/L3).
    // t2[b] computed per-thread in init() (17 uniform L2 loads, hidden
    // under the staging prologue).
    const float* gateT; const int* counts; const int* h2cm; u16* gated;
    int t2 = 0;
    __device__ void init(int b) {
        int cmax = h2cm[640 + b * 32];
        int suffix = 0, best = 0;
        bool found = false;
        for (int tt = 16; tt >= 1; --tt) {
            suffix += h2cm[b * 32 + tt];
            if (!found && tt <= cmax && suffix > 3600) { best = tt; found = true; }
        }
        t2 = found ? best : cmax;
    }
    __device__ void operator()(float acc, int b, int m, int n, int j) const {
        if (m >= SS || n >= 608) return;
        float r = 0.f;
        if (n < HIDH) {
            float g = gateT[((long)b * HIDH + n) * SS + m];
            int c = counts[(b * 100 + m / 5) * 120 + n / 5];
            float bv = (c >= t2) ? 1.f : 0.25f;
            float p = ((m % 5) == 4 || (n % 5) == 4) ? 0.f : 1.f;
            r = acc * g * bv * p;
        }
        gated[((long)(b * SS + m)) * 608 + n] = f2bu(r);
    }
    __device__ void finish(int, int, int) const {}
};
struct EpiOutB {         // out = gated@Wout + bout + x
    const float* bout; const float* x; float* out;
    __device__ void init(int) const {}
    __device__ void operator()(float acc, int b, int m, int n, int j) const {
        if (m >= 10000 || n >= DIMD) return;
        out[(long)m * DIMD + n] = acc + bout[n] + x[(long)m * DIMD + n];
    }
    __device__ void finish(int, int, int) const {}
};

// ---------------- cooperative-staged bf16 MFMA GEMM body ----------------
// FINAL (R13 configuration -- best measured, 205.5us).  NBUF per dispatch:
//   NBUF=3 (24KB, counted vmcnt(2), prefetch dist 2): qk_h (K=320,
//     steady-state dominated; R11 41.3us vs 44.8 at NBUF=2).
//   NBUF=2 (16KB, drain vmcnt(0), 8 blocks/CU): sc/attn@v/out
//     (R12/R13 measured best; R14's occupancy-arithmetic NBUF=3 variant
//     for attn@v/out was falsified, 207.8 vs 205.5).
// Proven elements: cooperative staging (waves 0,1->A rows, 2,3->B rows;
// 2 glds/wave/step), XOR swizzle (conflicts 2.1M->0, zero per-step cost),
// RAW s_barrier + compiler fence (rule-18), __expf silu.
// R9 lesson: glds staging is load-bearing (direct-to-reg = compiler won't
// pipeline scattered frag loads, 2x slower).  R1/R7 lesson: resident-wave
// count is the binding constraint; LDS/block is the currency.
// Sync per step: s_waitcnt vmcnt(N) lgkmcnt(0) [N=2 while >=1 step remains
// at NBUF=3, else 0] -> s_barrier -> fence -> prefetch into the buffer
// whose readers all drained before this barrier -> 4 ds_read + 4 MFMA.
// Swizzle (rule-21, both-sides with glds): LDS linear; GLOBAL source chunk
// c' = c ^ ((srow>>1)&3); read chunk l4 ^ ((l15>>1)&3) (compile-time per
// lane: frag row bases are multiples of 16).
// 1-D grid, XCD pinning (workgroup->XCD is round-robin on linear id):
//   MODE 0: batch g -> XCD g%8 (unbalanced for bound=20; reference only).
//   MODE 1: slice N per-XCD (TX groups).  MODE 2: slice M per-XCD.
//   MODE 3: BALANCED batch map for 20 batches (TY==8): XCD x gets batches
//           2x,2x+1 full + half of batch 16+(x&3) (row-band split keeps
//           scores->attn@v attnb tiles on the producing XCD).
// Early whole-block return is uniform and pre-barrier.  Staging has NO
// bounds checks: overruns read adjacent ws buffers (audited in-bounds for
// every call site); garbage only reaches acc rows/cols whose epilogue
// writes are guarded off; K-pads are real zeros.
template<int MODE, int NBUF, class Epi>
__device__ __forceinline__ void gemm_body(
        int lin, u16* __restrict__ S,
        const u16* __restrict__ A, const u16* __restrict__ Bt,
        int Kp, int lda, int ldb, long sA, long sB,
        int TX, int TY, int bound, Epi epi) {
    int xcd = lin & 7, i = lin >> 3;
    int bx, by, bz;
    if (MODE == 3) {                    // balanced 20-batch map (TY==8)
        int P = TX << 3;                // tiles per batch
        int half = P >> 1;
        int tl;
        if (i < 2 * P) {
            bz = (xcd << 1) + (i >= P ? 1 : 0);
            tl = (i >= P) ? i - P : i;
        } else {
            bz = 16 + (xcd & 3);
            tl = (i - 2 * P) + ((xcd & 4) ? half : 0);
        }
        bx = tl % TX; by = tl / TX;
    } else {
        int per = TX * TY;
        int w = i / per;
        int tl = i - w * per;
        int g = xcd + (w << 3);
        int tx = tl % TX, ty = tl / TX;
        if (MODE == 0)      { if (g >= bound) return; bx = tx; by = ty; bz = g; }
        else if (MODE == 1) { bx = g * TX + tx; if (bx >= bound) return; by = ty; bz = 0; }
        else                { by = g * TY + ty; if (by >= bound) return; bx = tx; bz = 0; }
    }

    A += (long)bz * sA; Bt += (long)bz * sB;
    int t = threadIdx.x, lane = t & 63, wave = t >> 6;
    int l15 = lane & 15, l4 = lane >> 4;
    int mw = (wave >> 1) << 5, nw = (wave & 1) << 5;
    int m0 = (by << 6) + mw;
    int n0 = (bx << 6) + nw;

    // staging: lane covers (row r=lane>>2, chunk c=lane&3) of a 16-row block;
    // source chunk XOR-swizzled: c' = c ^ ((r>>1)&3)
    int srow = lane >> 2;
    int scol = ((lane & 3) ^ ((srow >> 1) & 3)) << 3;
    const u16* gp0;
    int drow;
    if (wave < 2) {
        gp0 = A + (long)((by << 6) + (wave << 5) + srow) * lda + scol;
        drow = wave << 5;
    } else {
        gp0 = Bt + (long)((bx << 6) + ((wave - 2) << 5) + srow) * ldb + scol;
        drow = 64 + ((wave - 2) << 5);
    }
    const u16* gp1 = gp0 + (long)16 * (wave < 2 ? lda : ldb);
    u16* d0 = S + drow * 32;
    u16* d1 = S + (drow + 16) * 32;

    floatx4 acc[2][2];
#pragma unroll
    for (int i2 = 0; i2 < 2; ++i2)
#pragma unroll
        for (int j = 0; j < 2; ++j) acc[i2][j] = (floatx4){0.f, 0.f, 0.f, 0.f};

    int nsteps = Kp >> 5;
    // prologue: stage buffers 0..NBUF-2
    glds16(gp0, d0);
    glds16(gp1, d1);
    if constexpr (NBUF == 3) {
        if (nsteps > 1) { glds16(gp0 + 32, d0 + 4096); glds16(gp1 + 32, d1 + 4096); }
    }

    epi.init(bz);                              // hidden under staging latency

    // read chunk: frag row bases are multiples of 16 -> ((row>>1)&3) == ((l15>>1)&3)
    int rchunk = (l4 ^ ((l15 >> 1) & 3)) << 3;

    int bufc = 0;                              // current buffer index (si % NBUF)
    for (int si = 0; si < nsteps; ++si) {
        if constexpr (NBUF == 3) {
            if (si + 1 < nsteps)
                asm volatile("s_waitcnt vmcnt(2) lgkmcnt(0)" ::: "memory");
            else
                asm volatile("s_waitcnt vmcnt(0) lgkmcnt(0)" ::: "memory");
        } else {
            asm volatile("s_waitcnt vmcnt(0) lgkmcnt(0)" ::: "memory");
        }
        __builtin_amdgcn_s_barrier();
        asm volatile("" ::: "memory");         // pin ds_reads below barrier
        int kn = (si + NBUF - 1) << 5;
        if (kn < Kp) {                         // prefetch distance NBUF-1
            int bufp = (bufc == 0) ? NBUF - 1 : bufc - 1;   // (si+NBUF-1)%NBUF
            glds16(gp0 + kn, d0 + bufp * 4096);
            glds16(gp1 + kn, d1 + bufp * 4096);
        }
        const u16* SB = S + bufc * 4096;
        short8 a0 = *(const short8*)(SB + ((mw + l15) << 5) + rchunk);
        short8 a1 = *(const short8*)(SB + ((mw + 16 + l15) << 5) + rchunk);
        short8 b0 = *(const short8*)(SB + ((64 + nw + l15) << 5) + rchunk);
        short8 b1 = *(const short8*)(SB + ((64 + nw + 16 + l15) << 5) + rchunk);
        acc[0][0] = mfma_bf16(a0, b0, acc[0][0]);
        acc[0][1] = mfma_bf16(a0, b1, acc[0][1]);
        acc[1][0] = mfma_bf16(a1, b0, acc[1][0]);
        acc[1][1] = mfma_bf16(a1, b1, acc[1][1]);
        bufc = (bufc + 1 == NBUF) ? 0 : bufc + 1;
    }
#pragma unroll
    for (int i2 = 0; i2 < 2; ++i2) {
        int bm = m0 + (i2 << 4) + (l4 << 2);
#pragma unroll
        for (int j = 0; j < 2; ++j) {
            int bn = n0 + (j << 4) + l15;
#pragma unroll
            for (int r = 0; r < 4; ++r)
                epi(acc[i2][j][r], bz, bm + r, bn, j);
        }
    }
    epi.finish(bz, m0, n0);
}

// standalone wrapper (static LDS = NBUF*8KB)
template<int MODE, int NBUF, class Epi>
__global__ __launch_bounds__(256)
void gemm_nb(const u16* __restrict__ A, const u16* __restrict__ Bt,
             int Kp, int lda, int ldb, long sA, long sB,
             int TX, int TY, int bound, Epi epi) {
    __shared__ __align__(16) u16 S[NBUF * 4096];
    gemm_body<MODE, NBUF>(blockIdx.x, S, A, Bt, Kp, lda, ldb, sA, sB, TX, TY, bound, epi);
}

// merged qk-gemm (blocks [0,320)) + h-gemm (blocks [320,3360)).  Independent,
// both read nxb, both latency-bound -> overlap in one launch.  Offset
// 320%8==0 preserves the h-gemm's XCD slicing.  NBUF=3 (long-K config,
// R11-measured best).  Dynamic LDS 24KB.
__global__ __launch_bounds__(256)
void gemm_qk_h(const u16* __restrict__ nxb, const u16* __restrict__ Wqkb,
               const u16* __restrict__ WhT, EpiQKRot eq, EpiH eh) {
    extern __shared__ u16 S[];
    int lin = blockIdx.x;
    if (lin < 320)
        gemm_body<2, 3>(lin, S, nxb, Wqkb, 320, 320, 320, 0L, 0L, 2, 20, 157, eq);
    else
        gemm_body<1, 3>(lin - 320, S, WhT, nxb, 320, 320, 320, 0L, 0L, 20, 19, 157, eh);
}

// merged scores-gemm (blocks [0,1280), MODE 3 balanced, NBUF=2 residency
// config) + counts ([1280,2220)).  counts: 47 blocks per batch; per-block
// LDS h2-hist + max, one atomicAdd per bin per block into h2cm.
__global__ __launch_bounds__(256)
void gemm_sc(const u16* __restrict__ qb, const u16* __restrict__ kb, EpiAttnB ea,
             const float* __restrict__ gateT, const int* __restrict__ hist,
             const unsigned* __restrict__ gmaxu, int* __restrict__ counts,
             int* __restrict__ h2cm) {
    extern __shared__ u16 S[];
    int lin = blockIdx.x;
    if (lin < 1280) {
        gemm_body<3, 2>(lin, S, qb, kb, QKD, QKD, QKD,
                        (long)SS * QKD, (long)SS * QKD, 8, 8, BB, ea);
        return;
    }
    int cb = lin - 1280;
    int b = cb / 47, blk = cb - b * 47;
    int r = blk * 256 + threadIdx.x;
    int* h2l = (int*)S;
    int* smaxp = h2l + 17;
    if (threadIdx.x < 17) h2l[threadIdx.x] = 0;
    if (threadIdx.x == 0) *smaxp = 0;
    __syncthreads();
    int c = 0;
    if (r < 12000) {
        unsigned enc = gmaxu[b * 64];
        unsigned bits = (enc & 0x80000000u) ? (enc & 0x7FFFFFFFu) : ~enc;
        float gmax = floorf(__uint_as_float(bits));
        int suffix = 0, trim = 1;
        for (int tt = 128; tt >= 1; --tt) {
            suffix += hist[b * 256 + tt];
            if ((float)tt <= gmax && suffix > 90000) { trim = tt; break; }
        }
        float tr = (float)trim;
        int bi = r / 120, bj = r - bi * 120;
        const float* gb = gateT + (long)b * SS * HIDH;
#pragma unroll
        for (int cc = 0; cc < 4; ++cc)
#pragma unroll
            for (int rr = 0; rr < 4; ++rr) {
                float gv = gb[(long)(bj * 5 + cc) * SS + bi * 5 + rr];
                c += (fabsf(gv) >= tr) ? 1 : 0;
            }
        counts[b * 12000 + r] = c;
        if (c) atomicAdd(&h2l[c], 1);
    }
    int lmax = c;
    for (int off = 32; off; off >>= 1) {
        int o = __shfl_xor(lmax, off);
        lmax = lmax > o ? lmax : o;
    }
    if ((threadIdx.x & 63) == 0) atomicMax(smaxp, lmax);
    __syncthreads();
    if (threadIdx.x < 17 && h2l[threadIdx.x])
        atomicAdd(&h2cm[b * 32 + threadIdx.x], h2l[threadIdx.x]);
    if (threadIdx.x == 0) atomicMax(&h2cm[640 + b * 32], *smaxp);
}

extern "C" void kernel_launch(void* const* d_in, const int* in_sizes, int n_in,
                              void* d_out, int out_size, void* d_ws, size_t ws_size,
                              hipStream_t stream) {
    const float* x      = (const float*)d_in[0];
    const float* mask2  = (const float*)d_in[1];
    const float* ln_g   = (const float*)d_in[2];
    const float* ln_b   = (const float*)d_in[3];
    const float* Wh     = (const float*)d_in[4];
    const float* bh     = (const float*)d_in[5];
    const float* Wqk    = (const float*)d_in[6];
    const float* bqk    = (const float*)d_in[7];
    const float* gamma  = (const float*)d_in[8];
    const float* beta   = (const float*)d_in[9];
    const float* rel_emb= (const float*)d_in[10];
    const float* Wout   = (const float*)d_in[11];
    const float* bout   = (const float*)d_in[12];
    float* out = (float*)d_out;
    float* ws  = (float*)d_ws;

    // workspace layout (float offsets; all 16B-aligned)
    float* gateT  = ws;                            //  6,000,000 f
    float* bias   = ws + 6000000;                  //    250,000 f
    u16*   nxb    = (u16*)(ws + 6250000);          // 10000x320 u16
    u16*   WhT    = (u16*)(ws + 7850000);          //  1200x320 u16
    u16*   Wqkb   = (u16*)(ws + 8042000);          //   128x320 u16
    u16*   WoutT  = (u16*)(ws + 8062480);          //   300x608 u16
    u16*   qb     = (u16*)(ws + 8153680);          // 10000x128 u16
    u16*   kb     = (u16*)(ws + 8793680);          // 10000x128 u16
    u16*   attnb  = (u16*)(ws + 9433680);          // 20x500x512 u16
    u16*   vT     = (u16*)(ws + 11993680);         // 20x640x512 u16
    u16*   gatedb = (u16*)(ws + 15270480);         // 10000x608 u16
    int*   hist   = (int*)(ws + 21310480);         // 20 x 256-int stride
    unsigned* gmaxu = (unsigned*)(ws + 21315600);  // 20 x 64-uint stride
    int*   counts = (int*)(ws + 21316880);         //   240,000
    int*   h2cm   = (int*)(ws + 21556880);         // h2 20x32 + cmax 20x32

    // 1. prep + LN; also zeroes hist/gmaxu/h2cm
    prep_ln_kernel<<<5880, 256, 0, stream>>>(x, ln_g, ln_b, nxb, Wh, Wqk, Wout,
                                             rel_emb, WhT, Wqkb, WoutT, bias,
                                             hist, gmaxu, h2cm);

    // 2. MERGED: qk gemm + silu/rotary (M=10000,N=128,Kp=320; 320 blocks)
    //    || h gemm -> vT bf16 + gateT fp32 + fused hist/gmax
    //    (M=1200,N=10000,Kp=320; 3040 blocks).  NBUF=3 / 24KB.
    gemm_qk_h<<<3360, 256, 24576, stream>>>(
        nxb, Wqkb, WhT,
        EpiQKRot{bqk, gamma, beta, qb, kb},
        EpiH{bh, vT, gateT, hist, gmaxu});

    // 3. MERGED: scores -> attnb bf16 (MODE 3 balanced: each XCD 2.5
    //    batches, row-band split; 1280 blocks; NBUF=2 / 16KB)
    //    || counts (940 blocks)
    gemm_sc<<<2220, 256, 16384, stream>>>(
        qb, kb, EpiAttnB{bias, mask2, attnb},
        gateT, hist, gmaxu, counts, h2cm);

    // 4. attn@v + fused gate mask (per batch 500x640, Kp=512): MODE 3
    //    balanced (1600 blocks); row-band split matches scores so attnb
    //    tiles are read from the producing XCD's L2.  NBUF=2 / 16KB.
    //    t2[b] derived per-thread in epi.init from h2cm.
    gemm_nb<3, 2><<<1600, 256, 0, stream>>>(
        attnb, vT, 512, 512, 512,
        (long)SS * 512, (long)640 * 512, 10, 8, BB,
        EpiGateN{gateT, counts, h2cm, gatedb});

    // 5. out = gated@Wout + bout + x (M=10000, N=300, Kp=608):
    //    slice M over XCDs, TX=5 n-tiles.  NBUF=2 / 16KB.
    gemm_nb<2, 2><<<8 * 5 * 20, 256, 0, stream>>>(
        gatedb, WoutT, 608, 608, 608, 0L, 0L, 5, 20, 157, EpiOutB{bout, x, out});
}